// Round 12
// baseline (274.327 us; speedup 1.0000x reference)
//
#include <hip/hip_runtime.h>
#include <hip/hip_bf16.h>
#include <math.h>

// ---- problem constants ----
#define NB 256      // batch
#define NN 307      // vertices
#define NBN 78592   // NB*NN
#define LL 12       // sequence length
#define DDIM 16     // model dim
#define HISW 268    // 267 history cols + 1 zero pad (for float4)
#define HIS4 67     // HISW/4
#define NBRCAP 64   // per-row neighbor capacity (mean 9.2, 64 is ~18 sigma)
#define AGRP 24     // bn rows per 192-thread attn block: stage B = 24*8 = all 3 waves
#define ADTS 308    // AdT row stride (padded even for float2 alignment)

// ---- workspace layout (float offsets; every segment 16B-aligned) ----
#define OFF_XTCN 0u            // 15089664 ushorts [B,N,L,D] bf16 (=7544832 floats)
#define OFF_TEK  7544832u      //    49152 floats  te@Wk+bk (inside xtcn region)
#define OFF_G1   15089664u     //   943104 floats  [B,N,L]
#define OFF_ADT  16032768u     //    94688 floats  A_dyn^T [m][308]
#define OFF_TEQ  16127456u     //    49152 floats  [B,L,16]  (te@Wq+bq)/sqrt2
#define OFF_HIS  16176608u     //    82288 floats  [N,268]
#define OFF_NW   16258896u     //    19648 floats  nbr weights [N,64]
#define OFF_NIDX 16278544u     //    19648 ints    nbr indices [N,64]
#define OFF_NCNT 16298192u     //      320 ints    nbr counts
#define OFF_TEV  16298512u     //    49152 floats  te@Wv+bv
#define OFF_TEO  16347664u     //    49152 floats  te+bo

__device__ inline float4 mkf4(float a, float b, float c, float d) {
    float4 r; r.x = a; r.y = b; r.z = c; r.w = d; return r;
}
__device__ inline float bf_lo(unsigned u) { return __uint_as_float(u << 16); }
__device__ inline float bf_hi(unsigned u) { return __uint_as_float(u & 0xffff0000u); }

// ---------------------------------------------------------------------------
// K0 fused prep (block-specialized): his | TE tables | sparse A_st rows.
// ---------------------------------------------------------------------------
__global__ __launch_bounds__(256) void prep_kernel(
    const float* __restrict__ flow,
    const int* __restrict__ dayc, const int* __restrict__ weekc,
    const float* __restrict__ demb, const float* __restrict__ wemb,
    const float* __restrict__ Wq, const float* __restrict__ bq,
    const float* __restrict__ Wk, const float* __restrict__ bk,
    const float* __restrict__ Wv, const float* __restrict__ bv,
    const float* __restrict__ bo, const float* __restrict__ adj,
    float* __restrict__ his,
    float* __restrict__ TEQ, float* __restrict__ TEK,
    float* __restrict__ TEV, float* __restrict__ TEO,
    int* __restrict__ ncnt, int* __restrict__ nidx, float* __restrict__ nw) {
    __shared__ float sTE[16][16];
    int bx = blockIdx.x, t = threadIdx.x;
    if (bx < 322) {
        int e = bx * 256 + t;
        if (e < NN * HISW) {
            int n = e / HISW, j = e - n * HISW;
            float v = 0.f;
            if (j < LL) v = flow[n * LL + j];
            else if (j < 267) v = flow[((j - 11) * NN + n) * LL + 11];
            his[e] = v;
        }
    } else if (bx < 514) {
        int r = t >> 4, d = t & 15;
        int row = (bx - 322) * 16 + r;        // < 3072
        int b = row / LL, l = row - b * LL;
        int dc = dayc[b * LL + l], wc = weekc[b * LL + l];
        int i = d >> 1;
        float ang = (float)l * powf(10000.f, -0.125f * (float)i);
        float pe = (d & 1) ? cosf(ang) : sinf(ang);
        float te = demb[dc * DDIM + d] + wemb[wc * DDIM + d] + pe;
        sTE[r][d] = te;
        __syncthreads();
        float aq = bq[d], ak = bk[d], av = bv[d];
#pragma unroll
        for (int e = 0; e < 16; e++) {
            float x = sTE[r][e];
            aq += x * Wq[e * 16 + d];
            ak += x * Wk[e * 16 + d];
            av += x * Wv[e * 16 + d];
        }
        TEQ[row * 16 + d] = aq * 0.70710678118654752f;
        TEK[row * 16 + d] = ak;
        TEV[row * 16 + d] = av;
        TEO[row * 16 + d] = te + bo[d];
    } else {
        if (t < 64) {
            int n = bx - 514;
            float rs = 0.f;
            for (int m0 = 0; m0 < NN; m0 += 64) {
                int m = m0 + t;
                if (m < NN) rs += adj[n * NN + m];
            }
            for (int off = 32; off > 0; off >>= 1) rs += __shfl_xor(rs, off);
            float inv = 1.f / (rs + 1.f);
            int c = 0;
            for (int m0 = 0; m0 < NN; m0 += 64) {
                int m = m0 + t;
                float a = (m < NN) ? adj[n * NN + m] : 0.f;
                bool p = (a != 0.f);
                unsigned long long mask = __ballot(p);
                int pos = __popcll(mask & ((1ull << t) - 1ull));
                if (p && (c + pos) < NBRCAP) {
                    nidx[n * NBRCAP + c + pos] = m;
                    nw[n * NBRCAP + c + pos] = a * inv;
                }
                c += (int)__popcll(mask);
            }
            if (t == 0) ncnt[n] = c < NBRCAP ? c : NBRCAP;
        }
    }
}

// ---------------------------------------------------------------------------
// K1: A_dyn row-softmax of -dist, stored transposed AdT[m*308+n]
// ---------------------------------------------------------------------------
__global__ __launch_bounds__(256) void adyn_kernel(const float* __restrict__ his,
                                                   float* __restrict__ AdT) {
    __shared__ float4 sh[HIS4];
    __shared__ float red[256];
    int n = blockIdx.x, t = threadIdx.x;
    if (t < HIS4) sh[t] = reinterpret_cast<const float4*>(his)[n * HIS4 + t];
    __syncthreads();

    float e0 = 0.f, e1 = 0.f, lsum = 0.f;
    {
        const float4* row = reinterpret_cast<const float4*>(his) + t * HIS4;
        float4 acc = mkf4(0.f, 0.f, 0.f, 0.f);
        for (int j = 0; j < HIS4; j++) {
            float4 a = sh[j], b = row[j];
            float dx = a.x - b.x, dy = a.y - b.y, dz = a.z - b.z, dw = a.w - b.w;
            acc.x += dx * dx; acc.y += dy * dy; acc.z += dz * dz; acc.w += dw * dw;
        }
        float d2 = (acc.x + acc.y) + (acc.z + acc.w);
        e0 = __expf(-sqrtf(fmaxf(d2, 0.f)));
        lsum += e0;
    }
    int m1 = t + 256;
    if (m1 < NN) {
        const float4* row = reinterpret_cast<const float4*>(his) + m1 * HIS4;
        float4 acc = mkf4(0.f, 0.f, 0.f, 0.f);
        for (int j = 0; j < HIS4; j++) {
            float4 a = sh[j], b = row[j];
            float dx = a.x - b.x, dy = a.y - b.y, dz = a.z - b.z, dw = a.w - b.w;
            acc.x += dx * dx; acc.y += dy * dy; acc.z += dz * dz; acc.w += dw * dw;
        }
        float d2 = (acc.x + acc.y) + (acc.z + acc.w);
        e1 = __expf(-sqrtf(fmaxf(d2, 0.f)));
        lsum += e1;
    }
    red[t] = lsum;
    __syncthreads();
    for (int s = 128; s > 0; s >>= 1) {
        if (t < s) red[t] += red[t + s];
        __syncthreads();
    }
    float inv = 1.f / red[0];
    AdT[t * ADTS + n] = e0 * inv;
    if (m1 < NN) AdT[m1 * ADTS + n] = e1 * inv;
}

// ---------------------------------------------------------------------------
// K3 v9: temporal self-attention. AGRP=24 @ 192 threads:
//   stage B = 24 bn x 8 heads = 192 lanes -> ALL 3 waves active (v8 idled
//   wave 2 through the expensive stage), stage C = 288 jobs / 192 lanes.
//   Blocks 4912 -> 3275: 33% less sT staging + barrier overhead.
// LDS ~30.4KB -> 5 blocks/CU = 15 stage-B waves/CU (v8: 14).
// ---------------------------------------------------------------------------
__global__ __launch_bounds__(192) void attn_kernel(
    const float* __restrict__ flow,
    const float* __restrict__ TEQ, const float* __restrict__ TEK,
    const float* __restrict__ TEV, const float* __restrict__ TEO,
    const float* __restrict__ Wq, const float* __restrict__ Wk,
    const float* __restrict__ Wv, const float* __restrict__ Wo,
    unsigned short* __restrict__ xtcn) {
    __shared__ __align__(16) float sWo[256];
    __shared__ __align__(16) float sWs[48];        // wq1/sqrt2, wk1, wv1 col-sums
    __shared__ __align__(16) float sT[4][24][16];  // TEQ/TEK/TEV/TEO, 2 b's
    __shared__ __align__(16) float sA[AGRP][LL][20];

    const int t = threadIdx.x;
    const int bn0 = blockIdx.x * AGRP;
    const int b0 = bn0 / NN;
    const int rbase = b0 * LL;

    for (int id = t; id < 256; id += 192) sWo[id] = Wo[id];
    if (t < 48) {
        int mat = t >> 4, d = t & 15;
        const float* W = (mat == 0) ? Wq : (mat == 1) ? Wk : Wv;
        float s = 0.f;
#pragma unroll
        for (int e = 0; e < 16; e++) s += W[e * 16 + d];
        sWs[t] = (mat == 0) ? s * 0.70710678118654752f : s;
    }
    // stage TE tables: 4 tables x 24 rows x 16 floats = 384 float4 chunks
#pragma unroll
    for (int p = 0; p < 2; p++) {
        int idx = t + p * 192;
        int tab = idx / 96, rr4 = idx - tab * 96;
        int rr = rr4 >> 2, j = rr4 & 3;
        int row = rbase + rr;
        if (row < NB * LL) {
            const float* src = (tab == 0) ? TEQ : (tab == 1) ? TEK : (tab == 2) ? TEV : TEO;
            reinterpret_cast<float4*>(&sT[tab][rr][0])[j] =
                reinterpret_cast<const float4*>(src + row * 16)[j];
        }
    }
    __syncthreads();

    // ---- stage B: all 192 lanes = (g,h) ----
    {
        int g = t >> 3, h = t & 7;
        int bn = bn0 + g;
        if (bn < NBN) {
            int b = bn / NN;
            int lb = (b - b0) * LL;
            float f[12];
            {
                const float4* fr = reinterpret_cast<const float4*>(flow + bn * LL);
                float4 f0 = fr[0], f1 = fr[1], f2 = fr[2];
                f[0] = f0.x; f[1] = f0.y; f[2] = f0.z; f[3] = f0.w;
                f[4] = f1.x; f[5] = f1.y; f[6] = f1.z; f[7] = f1.w;
                f[8] = f2.x; f[9] = f2.y; f[10] = f2.z; f[11] = f2.w;
            }
            float wqx = sWs[2 * h], wqy = sWs[2 * h + 1];
            float wkx = sWs[16 + 2 * h], wky = sWs[16 + 2 * h + 1];
            float wvx = sWs[32 + 2 * h], wvy = sWs[32 + 2 * h + 1];
            float kx[12], ky[12], vx[12], vy[12];
#pragma unroll
            for (int m = 0; m < LL; m++) {
                float2 tk = *reinterpret_cast<const float2*>(&sT[1][lb + m][2 * h]);
                float2 tv = *reinterpret_cast<const float2*>(&sT[2][lb + m][2 * h]);
                kx[m] = tk.x + f[m] * wkx; ky[m] = tk.y + f[m] * wky;
                vx[m] = tv.x + f[m] * wvx; vy[m] = tv.y + f[m] * wvy;
            }
#pragma unroll
            for (int l = 0; l < LL; l++) {
                float2 tq = *reinterpret_cast<const float2*>(&sT[0][lb + l][2 * h]);
                float qx = tq.x + f[l] * wqx, qy = tq.y + f[l] * wqy;
                float s[12];
                float sum = 0.f;
#pragma unroll
                for (int m = 0; m < LL; m++) {
                    s[m] = __expf(qx * kx[m] + qy * ky[m]);  // 1/sqrt2 folded into q
                    sum += s[m];
                }
                float a0 = 0.f, a1 = 0.f;
#pragma unroll
                for (int m = 0; m < LL; m++) { a0 += s[m] * vx[m]; a1 += s[m] * vy[m]; }
                float inv = 1.f / sum;
                float2 r; r.x = a0 * inv; r.y = a1 * inv;
                *reinterpret_cast<float2*>(&sA[g][l][2 * h]) = r;
            }
        }
    }
    __syncthreads();

    // ---- stage C: 288 jobs = (g,l) over 192 lanes, 2 passes ----
#pragma unroll
    for (int p = 0; p < 2; p++) {
        int jb = t + p * 192;
        if (jb < AGRP * LL) {
            int g = jb / LL, l = jb - g * LL;
            int bn = bn0 + g;
            if (bn < NBN) {
                int b = bn / NN;
                int lb = (b - b0) * LL;
                float f = flow[bn * LL + l];
                float att[16];
                const float4* ar = reinterpret_cast<const float4*>(&sA[g][l][0]);
                float4 a0 = ar[0], a1 = ar[1], a2 = ar[2], a3 = ar[3];
                att[0] = a0.x; att[1] = a0.y; att[2] = a0.z; att[3] = a0.w;
                att[4] = a1.x; att[5] = a1.y; att[6] = a1.z; att[7] = a1.w;
                att[8] = a2.x; att[9] = a2.y; att[10] = a2.z; att[11] = a2.w;
                att[12] = a3.x; att[13] = a3.y; att[14] = a3.z; att[15] = a3.w;
                float o[16];
                const float4* to4 = reinterpret_cast<const float4*>(&sT[3][lb + l][0]);
#pragma unroll
                for (int j = 0; j < 4; j++) {
                    float4 a = to4[j];
                    o[4 * j] = a.x; o[4 * j + 1] = a.y; o[4 * j + 2] = a.z; o[4 * j + 3] = a.w;
                }
#pragma unroll
                for (int e = 0; e < 16; e++) {
                    float ae = att[e];
                    const float4* wo = reinterpret_cast<const float4*>(&sWo[e * 16]);
#pragma unroll
                    for (int j = 0; j < 4; j++) {
                        float4 w = wo[j];
                        o[4 * j] += ae * w.x; o[4 * j + 1] += ae * w.y;
                        o[4 * j + 2] += ae * w.z; o[4 * j + 3] += ae * w.w;
                    }
                }
                unsigned pk[8];
#pragma unroll
                for (int j = 0; j < 8; j++) {
                    unsigned u0 = __float_as_uint(o[2 * j] + f) + 0x8000u;
                    unsigned u1 = __float_as_uint(o[2 * j + 1] + f) + 0x8000u;
                    pk[j] = (u0 >> 16) | (u1 & 0xffff0000u);
                }
                uint4* dst = reinterpret_cast<uint4*>(xtcn + (size_t)bn * 192 + l * 16);
                uint4 d0; d0.x = pk[0]; d0.y = pk[1]; d0.z = pk[2]; d0.w = pk[3];
                uint4 d1; d1.x = pk[4]; d1.y = pk[5]; d1.z = pk[6]; d1.w = pk[7];
                dst[0] = d0; dst[1] = d1;
            }
        }
    }
}

// ---------------------------------------------------------------------------
// K4 v4: G1 = A_dyn @ flow[b], 2 batches per block; flow via scalar loads.
// ---------------------------------------------------------------------------
__global__ __launch_bounds__(256) void g1_kernel(const float* __restrict__ flow,
                                                 const float* __restrict__ AdT,
                                                 float* __restrict__ G1) {
    int bp = blockIdx.x, nt = blockIdx.y, t = threadIdx.x;
    int lane = t & 63;
    int l0 = (t >> 6) * 3;
    int l0u = __builtin_amdgcn_readfirstlane(l0);
    int n = nt * 128 + 2 * lane;
    int b0 = 2 * bp;
    const float* fb0 = flow + (size_t)b0 * (NN * LL);
    const float* fb1 = fb0 + NN * LL;

    float a000 = 0.f, a001 = 0.f, a002 = 0.f;
    float a010 = 0.f, a011 = 0.f, a012 = 0.f;
    float a100 = 0.f, a101 = 0.f, a102 = 0.f;
    float a110 = 0.f, a111 = 0.f, a112 = 0.f;
#pragma unroll 4
    for (int m = 0; m < NN; m++) {
        float2 w = reinterpret_cast<const float2*>(AdT + (size_t)m * ADTS + nt * 128)[lane];
        const float* r0 = fb0 + m * LL + l0u;
        const float* r1 = fb1 + m * LL + l0u;
        float p0 = r0[0], p1 = r0[1], p2 = r0[2];
        float q0 = r1[0], q1 = r1[1], q2 = r1[2];
        a000 += w.x * p0; a001 += w.x * p1; a002 += w.x * p2;
        a010 += w.y * p0; a011 += w.y * p1; a012 += w.y * p2;
        a100 += w.x * q0; a101 += w.x * q1; a102 += w.x * q2;
        a110 += w.y * q0; a111 += w.y * q1; a112 += w.y * q2;
    }
    if (n < NN) {
        float* d0 = G1 + ((size_t)b0 * NN + n) * LL + l0;
        d0[0] = a000; d0[1] = a001; d0[2] = a002;
        float* d1 = G1 + ((size_t)(b0 + 1) * NN + n) * LL + l0;
        d1[0] = a100; d1[1] = a101; d1[2] = a102;
    }
    if (n + 1 < NN) {
        float* d0 = G1 + ((size_t)b0 * NN + n + 1) * LL + l0;
        d0[0] = a010; d0[1] = a011; d0[2] = a012;
        float* d1 = G1 + ((size_t)(b0 + 1) * NN + n + 1) * LL + l0;
        d1[0] = a110; d1[1] = a111; d1[2] = a112;
    }
}

// ---------------------------------------------------------------------------
// K5 v9 (unchanged from R11): fused graph-mix + per-vertex MLP.
// ---------------------------------------------------------------------------
__global__ __launch_bounds__(256) void final_kernel(
    const unsigned short* __restrict__ xtcn, const float* __restrict__ G1,
    const float* __restrict__ Wg, const float* __restrict__ Wt,
    const float* __restrict__ bg, const float* __restrict__ W1,
    const float* __restrict__ b1, const float* __restrict__ W2,
    const float* __restrict__ b2, const int* __restrict__ ncnt,
    const int* __restrict__ nidx, const float* __restrict__ nw,
    float* __restrict__ out) {
    __shared__ __align__(16) float sWt[512];
    __shared__ __align__(16) float sW1T[288];     // [oo][c], row stride 36
    __shared__ __align__(16) float sWg[32];
    __shared__ __align__(16) float sBg[32];
    __shared__ __align__(16) float sB1[8], sW2[8];
    __shared__ __align__(16) float sG1[4][12];
    __shared__ int sNid[64];
    __shared__ float sNw[64];
    __shared__ __align__(16) float sY[4][240];      // stride 20 per l
    __shared__ __align__(16) float4 sHID[4][120];   // stride 10 float4 per l
    __shared__ float sH1[4][96];

    int t = threadIdx.x;
    int by = blockIdx.x;          // batch group (XCD selector)
    int n  = blockIdx.y;          // vertex
    int w = t >> 6, t64 = t & 63;
    int b = by * 4 + w;

    // ---- staging ----
    {
        float v = W1[n * 256 + t];               // t = c*8+oo
        sW1T[(t & 7) * 36 + (t >> 3)] = v;       // -> [oo][c]
    }
    sWt[t] = Wt[t];
    sWt[t + 256] = Wt[t + 256];
    if (t < 32) sWg[t] = Wg[t];
    else if (t < 64) sBg[t - 32] = bg[t - 32];
    else if (t < 72) sB1[t - 64] = b1[n * 8 + (t - 64)];
    else if (t < 80) sW2[t - 72] = W2[n * 8 + (t - 72)];
    else if (t < 144) sNid[t - 80] = nidx[n * NBRCAP + (t - 80)];
    else if (t < 208) sNw[t - 144] = nw[n * NBRCAP + (t - 144)];
    if (t < 48) {
        int j = t / 12, l = t - j * 12;
        sG1[j][l] = G1[((size_t)(by * 4 + j) * NN + n) * LL + l];
    }
    float vb2 = b2[n];
    int cnt = ncnt[n];
    __syncthreads();

    // ---- sparse gather (bf16): lane t64<48 owns elements 4*t64..4*t64+3 ----
    if (t64 < 48) {
        float y0 = 0.f, y1 = 0.f, y2 = 0.f, y3 = 0.f;
        const unsigned short* base = xtcn + (size_t)b * NN * 192;
        int i = 0;
        for (; i + 3 < cnt; i += 4) {
            int m0 = sNid[i], m1 = sNid[i + 1], m2 = sNid[i + 2], m3 = sNid[i + 3];
            float w0 = sNw[i], w1 = sNw[i + 1], w2 = sNw[i + 2], w3 = sNw[i + 3];
            uint2 p0 = reinterpret_cast<const uint2*>(base + m0 * 192)[t64];
            uint2 p1 = reinterpret_cast<const uint2*>(base + m1 * 192)[t64];
            uint2 p2 = reinterpret_cast<const uint2*>(base + m2 * 192)[t64];
            uint2 p3 = reinterpret_cast<const uint2*>(base + m3 * 192)[t64];
            y0 += w0 * bf_lo(p0.x) + w1 * bf_lo(p1.x) + w2 * bf_lo(p2.x) + w3 * bf_lo(p3.x);
            y1 += w0 * bf_hi(p0.x) + w1 * bf_hi(p1.x) + w2 * bf_hi(p2.x) + w3 * bf_hi(p3.x);
            y2 += w0 * bf_lo(p0.y) + w1 * bf_lo(p1.y) + w2 * bf_lo(p2.y) + w3 * bf_lo(p3.y);
            y3 += w0 * bf_hi(p0.y) + w1 * bf_hi(p1.y) + w2 * bf_hi(p2.y) + w3 * bf_hi(p3.y);
        }
        for (; i < cnt; i++) {
            int m0 = sNid[i];
            float w0 = sNw[i];
            uint2 p0 = reinterpret_cast<const uint2*>(base + m0 * 192)[t64];
            y0 += w0 * bf_lo(p0.x); y1 += w0 * bf_hi(p0.x);
            y2 += w0 * bf_lo(p0.y); y3 += w0 * bf_hi(p0.y);
        }
        int l = t64 >> 2, p = t64 & 3;
        reinterpret_cast<float4*>(&sY[w][l * 20])[p] = mkf4(y0, y1, y2, y3);
    }
    __syncthreads();

    // ---- hid = relu(G1*Wg + y@Wt + bg): 384 jobs over 256 lanes ----
#pragma unroll
    for (int p = 0; p < 2; p++) {
        int jb = t + p * 256;
        if (jb < 384) {
            int w2 = jb / 96, c = jb - w2 * 96;
            int l = c >> 3, ch = c & 7;
            float g = sG1[w2][l];
            float4 wg = reinterpret_cast<const float4*>(sWg)[ch];
            float4 acc = reinterpret_cast<const float4*>(sBg)[ch];
            acc.x += g * wg.x; acc.y += g * wg.y; acc.z += g * wg.z; acc.w += g * wg.w;
            const float4* yr = reinterpret_cast<const float4*>(&sY[w2][l * 20]);
            float4 v0 = yr[0], v1 = yr[1], v2 = yr[2], v3 = yr[3];
            float ye[16] = {v0.x, v0.y, v0.z, v0.w, v1.x, v1.y, v1.z, v1.w,
                            v2.x, v2.y, v2.z, v2.w, v3.x, v3.y, v3.z, v3.w};
#pragma unroll
            for (int d = 0; d < 16; d++) {
                float4 wt = reinterpret_cast<const float4*>(sWt)[d * 8 + ch];
                acc.x += ye[d] * wt.x; acc.y += ye[d] * wt.y;
                acc.z += ye[d] * wt.z; acc.w += ye[d] * wt.w;
            }
            acc.x = fmaxf(acc.x, 0.f); acc.y = fmaxf(acc.y, 0.f);
            acc.z = fmaxf(acc.z, 0.f); acc.w = fmaxf(acc.w, 0.f);
            sHID[w2][l * 10 + ch] = acc;
        }
    }
    __syncthreads();

    // ---- h1 = relu(hid @ W1[n] + b1[n]): 384 jobs, W1T b128 reads ----
#pragma unroll
    for (int p = 0; p < 2; p++) {
        int jb = t + p * 256;
        if (jb < 384) {
            int w2 = jb / 96, o = jb - w2 * 96;
            int l = o >> 3, oo = o & 7;
            float acc = sB1[oo];
            float he[32];
#pragma unroll
            for (int k = 0; k < 8; k++) {
                float4 hv = sHID[w2][l * 10 + k];
                he[4 * k + 0] = hv.x; he[4 * k + 1] = hv.y;
                he[4 * k + 2] = hv.z; he[4 * k + 3] = hv.w;
            }
            const float4* w1r = reinterpret_cast<const float4*>(&sW1T[oo * 36]);
#pragma unroll
            for (int k = 0; k < 8; k++) {
                float4 wv = w1r[k];
                acc += he[4 * k] * wv.x + he[4 * k + 1] * wv.y
                     + he[4 * k + 2] * wv.z + he[4 * k + 3] * wv.w;
            }
            sH1[w2][o] = fmaxf(acc, 0.f);
        }
    }
    __syncthreads();

    // ---- out = h1 @ W2[n] + b2[n]: 48 jobs ----
    if (t < 48) {
        int w2 = t / 12, l = t - w2 * 12;
        const float4* h4 = reinterpret_cast<const float4*>(&sH1[w2][l * 8]);
        float4 ha = h4[0], hb = h4[1];
        const float4* w4 = reinterpret_cast<const float4*>(sW2);
        float4 wa = w4[0], wb = w4[1];
        float acc = vb2 + ha.x * wa.x + ha.y * wa.y + ha.z * wa.z + ha.w * wa.w
                        + hb.x * wb.x + hb.y * wb.y + hb.z * wb.z + hb.w * wb.w;
        out[((size_t)(by * 4 + w2) * NN + n) * LL + l] = acc;
    }
}

// ---------------------------------------------------------------------------
extern "C" void kernel_launch(void* const* d_in, const int* in_sizes, int n_in,
                              void* d_out, int out_size, void* d_ws, size_t ws_size,
                              hipStream_t stream) {
    const float* flow = (const float*)d_in[0];
    const int* dayc   = (const int*)d_in[1];
    const int* weekc  = (const int*)d_in[2];
    const float* adj  = (const float*)d_in[3];
    const float* demb = (const float*)d_in[4];
    const float* wemb = (const float*)d_in[5];
    const float* Wq = (const float*)d_in[6];  const float* bq = (const float*)d_in[7];
    const float* Wk = (const float*)d_in[8];  const float* bk = (const float*)d_in[9];
    const float* Wv = (const float*)d_in[10]; const float* bv = (const float*)d_in[11];
    const float* Wo = (const float*)d_in[12]; const float* bo = (const float*)d_in[13];
    const float* Wg = (const float*)d_in[14]; const float* Wt = (const float*)d_in[15];
    const float* bg = (const float*)d_in[16];
    const float* W1 = (const float*)d_in[17]; const float* b1 = (const float*)d_in[18];
    const float* W2 = (const float*)d_in[19]; const float* b2 = (const float*)d_in[20];
    float* out = (float*)d_out;
    float* ws  = (float*)d_ws;

    unsigned short* xtcn = (unsigned short*)(ws + 0);   // bf16 region
    float* TEK  = ws + OFF_TEK;   // upper half of xtcn float region
    float* G1   = ws + OFF_G1;
    float* AdT  = ws + OFF_ADT;
    float* TEQ  = ws + OFF_TEQ;
    float* TEV  = ws + OFF_TEV;
    float* TEO  = ws + OFF_TEO;
    float* his  = ws + OFF_HIS;
    float* nw   = ws + OFF_NW;
    int*   nidx = (int*)(ws + OFF_NIDX);
    int*   ncnt = (int*)(ws + OFF_NCNT);

    prep_kernel<<<821, 256, 0, stream>>>(flow, dayc, weekc, demb, wemb,
                                         Wq, bq, Wk, bk, Wv, bv, bo, adj,
                                         his, TEQ, TEK, TEV, TEO, ncnt, nidx, nw);
    adyn_kernel<<<NN, 256, 0, stream>>>(his, AdT);
    attn_kernel<<<(NBN + AGRP - 1) / AGRP, 192, 0, stream>>>(flow, TEQ, TEK, TEV, TEO,
                                                             Wq, Wk, Wv, Wo, xtcn);
    g1_kernel<<<dim3(NB / 2, 3), 256, 0, stream>>>(flow, AdT, G1);
    final_kernel<<<dim3(64, NN), 256, 0, stream>>>(xtcn, G1, Wg, Wt, bg, W1, b1, W2, b2,
                                                   ncnt, nidx, nw, out);
}

// Round 13
// 265.373 us; speedup vs baseline: 1.0337x; 1.0337x over previous
//
#include <hip/hip_runtime.h>
#include <hip/hip_bf16.h>
#include <math.h>

// ---- problem constants ----
#define NB 256      // batch
#define NN 307      // vertices
#define NBN 78592   // NB*NN
#define LL 12       // sequence length
#define DDIM 16     // model dim
#define HISW 268    // 267 history cols + 1 zero pad (for float4)
#define HIS4 67     // HISW/4
#define NBRCAP 64   // per-row neighbor capacity (mean 9.2, 64 is ~18 sigma)
#define AGRP 16     // bn rows per 192-thread attn block (best measured: R8/R9)
#define ADTS 308    // AdT row stride (padded even for float2 alignment)

// ---- workspace layout (float offsets; every segment 16B-aligned) ----
#define OFF_XTCN 0u            // 15089664 ushorts [B,N,L,D] bf16 (=7544832 floats)
#define OFF_TEK  7544832u      //    49152 floats  te@Wk+bk (inside xtcn region)
#define OFF_G1   15089664u     //   943104 floats  [B,N,L]
#define OFF_ADT  16032768u     //    94688 floats  A_dyn^T [m][308]
#define OFF_TEQ  16127456u     //    49152 floats  [B,L,16]  (te@Wq+bq)/sqrt2
#define OFF_HIS  16176608u     //    82288 floats  [N,268]
#define OFF_NW   16258896u     //    19648 floats  nbr weights [N,64]
#define OFF_NIDX 16278544u     //    19648 ints    nbr indices [N,64]
#define OFF_NCNT 16298192u     //      320 ints    nbr counts
#define OFF_TEV  16298512u     //    49152 floats  te@Wv+bv
#define OFF_TEO  16347664u     //    49152 floats  te+bo

__device__ inline float4 mkf4(float a, float b, float c, float d) {
    float4 r; r.x = a; r.y = b; r.z = c; r.w = d; return r;
}
__device__ inline float bf_lo(unsigned u) { return __uint_as_float(u << 16); }
__device__ inline float bf_hi(unsigned u) { return __uint_as_float(u & 0xffff0000u); }

// ---------------------------------------------------------------------------
// K0 fused prep (block-specialized): his | TE tables | sparse A_st rows.
// ---------------------------------------------------------------------------
__global__ __launch_bounds__(256) void prep_kernel(
    const float* __restrict__ flow,
    const int* __restrict__ dayc, const int* __restrict__ weekc,
    const float* __restrict__ demb, const float* __restrict__ wemb,
    const float* __restrict__ Wq, const float* __restrict__ bq,
    const float* __restrict__ Wk, const float* __restrict__ bk,
    const float* __restrict__ Wv, const float* __restrict__ bv,
    const float* __restrict__ bo, const float* __restrict__ adj,
    float* __restrict__ his,
    float* __restrict__ TEQ, float* __restrict__ TEK,
    float* __restrict__ TEV, float* __restrict__ TEO,
    int* __restrict__ ncnt, int* __restrict__ nidx, float* __restrict__ nw) {
    __shared__ float sTE[16][16];
    int bx = blockIdx.x, t = threadIdx.x;
    if (bx < 322) {
        int e = bx * 256 + t;
        if (e < NN * HISW) {
            int n = e / HISW, j = e - n * HISW;
            float v = 0.f;
            if (j < LL) v = flow[n * LL + j];
            else if (j < 267) v = flow[((j - 11) * NN + n) * LL + 11];
            his[e] = v;
        }
    } else if (bx < 514) {
        int r = t >> 4, d = t & 15;
        int row = (bx - 322) * 16 + r;        // < 3072
        int b = row / LL, l = row - b * LL;
        int dc = dayc[b * LL + l], wc = weekc[b * LL + l];
        int i = d >> 1;
        float ang = (float)l * powf(10000.f, -0.125f * (float)i);
        float pe = (d & 1) ? cosf(ang) : sinf(ang);
        float te = demb[dc * DDIM + d] + wemb[wc * DDIM + d] + pe;
        sTE[r][d] = te;
        __syncthreads();
        float aq = bq[d], ak = bk[d], av = bv[d];
#pragma unroll
        for (int e = 0; e < 16; e++) {
            float x = sTE[r][e];
            aq += x * Wq[e * 16 + d];
            ak += x * Wk[e * 16 + d];
            av += x * Wv[e * 16 + d];
        }
        TEQ[row * 16 + d] = aq * 0.70710678118654752f;
        TEK[row * 16 + d] = ak;
        TEV[row * 16 + d] = av;
        TEO[row * 16 + d] = te + bo[d];
    } else {
        if (t < 64) {
            int n = bx - 514;
            float rs = 0.f;
            for (int m0 = 0; m0 < NN; m0 += 64) {
                int m = m0 + t;
                if (m < NN) rs += adj[n * NN + m];
            }
            for (int off = 32; off > 0; off >>= 1) rs += __shfl_xor(rs, off);
            float inv = 1.f / (rs + 1.f);
            int c = 0;
            for (int m0 = 0; m0 < NN; m0 += 64) {
                int m = m0 + t;
                float a = (m < NN) ? adj[n * NN + m] : 0.f;
                bool p = (a != 0.f);
                unsigned long long mask = __ballot(p);
                int pos = __popcll(mask & ((1ull << t) - 1ull));
                if (p && (c + pos) < NBRCAP) {
                    nidx[n * NBRCAP + c + pos] = m;
                    nw[n * NBRCAP + c + pos] = a * inv;
                }
                c += (int)__popcll(mask);
            }
            if (t == 0) ncnt[n] = c < NBRCAP ? c : NBRCAP;
        }
    }
}

// ---------------------------------------------------------------------------
// K1: A_dyn row-softmax of -dist, stored transposed AdT[m*308+n]
// ---------------------------------------------------------------------------
__global__ __launch_bounds__(256) void adyn_kernel(const float* __restrict__ his,
                                                   float* __restrict__ AdT) {
    __shared__ float4 sh[HIS4];
    __shared__ float red[256];
    int n = blockIdx.x, t = threadIdx.x;
    if (t < HIS4) sh[t] = reinterpret_cast<const float4*>(his)[n * HIS4 + t];
    __syncthreads();

    float e0 = 0.f, e1 = 0.f, lsum = 0.f;
    {
        const float4* row = reinterpret_cast<const float4*>(his) + t * HIS4;
        float4 acc = mkf4(0.f, 0.f, 0.f, 0.f);
        for (int j = 0; j < HIS4; j++) {
            float4 a = sh[j], b = row[j];
            float dx = a.x - b.x, dy = a.y - b.y, dz = a.z - b.z, dw = a.w - b.w;
            acc.x += dx * dx; acc.y += dy * dy; acc.z += dz * dz; acc.w += dw * dw;
        }
        float d2 = (acc.x + acc.y) + (acc.z + acc.w);
        e0 = __expf(-sqrtf(fmaxf(d2, 0.f)));
        lsum += e0;
    }
    int m1 = t + 256;
    if (m1 < NN) {
        const float4* row = reinterpret_cast<const float4*>(his) + m1 * HIS4;
        float4 acc = mkf4(0.f, 0.f, 0.f, 0.f);
        for (int j = 0; j < HIS4; j++) {
            float4 a = sh[j], b = row[j];
            float dx = a.x - b.x, dy = a.y - b.y, dz = a.z - b.z, dw = a.w - b.w;
            acc.x += dx * dx; acc.y += dy * dy; acc.z += dz * dz; acc.w += dw * dw;
        }
        float d2 = (acc.x + acc.y) + (acc.z + acc.w);
        e1 = __expf(-sqrtf(fmaxf(d2, 0.f)));
        lsum += e1;
    }
    red[t] = lsum;
    __syncthreads();
    for (int s = 128; s > 0; s >>= 1) {
        if (t < s) red[t] += red[t + s];
        __syncthreads();
    }
    float inv = 1.f / red[0];
    AdT[t * ADTS + n] = e0 * inv;
    if (m1 < NN) AdT[m1 * ADTS + n] = e1 * inv;
}

// ---------------------------------------------------------------------------
// K3 v8 (best measured, R8/R9): temporal self-attention, head-lane
// formulation + LDS-staged TE. AGRP=16, 192 threads.
// ---------------------------------------------------------------------------
__global__ __launch_bounds__(192) void attn_kernel(
    const float* __restrict__ flow,
    const float* __restrict__ TEQ, const float* __restrict__ TEK,
    const float* __restrict__ TEV, const float* __restrict__ TEO,
    const float* __restrict__ Wq, const float* __restrict__ Wk,
    const float* __restrict__ Wv, const float* __restrict__ Wo,
    unsigned short* __restrict__ xtcn) {
    __shared__ __align__(16) float sWo[256];
    __shared__ __align__(16) float sWs[48];        // wq1/sqrt2, wk1, wv1 col-sums
    __shared__ __align__(16) float sT[4][24][16];  // TEQ/TEK/TEV/TEO, 2 b's
    __shared__ __align__(16) float sA[AGRP][LL][20];

    const int t = threadIdx.x;
    const int bn0 = blockIdx.x * AGRP;
    const int b0 = bn0 / NN;
    const int rbase = b0 * LL;

    for (int id = t; id < 256; id += 192) sWo[id] = Wo[id];
    if (t < 48) {
        int mat = t >> 4, d = t & 15;
        const float* W = (mat == 0) ? Wq : (mat == 1) ? Wk : Wv;
        float s = 0.f;
#pragma unroll
        for (int e = 0; e < 16; e++) s += W[e * 16 + d];
        sWs[t] = (mat == 0) ? s * 0.70710678118654752f : s;
    }
    // stage TE tables: 4 tables x 24 rows x 16 floats = 384 float4 chunks
#pragma unroll
    for (int p = 0; p < 2; p++) {
        int idx = t + p * 192;
        int tab = idx / 96, rr4 = idx - tab * 96;
        int rr = rr4 >> 2, j = rr4 & 3;
        int row = rbase + rr;
        if (row < NB * LL) {
            const float* src = (tab == 0) ? TEQ : (tab == 1) ? TEK : (tab == 2) ? TEV : TEO;
            reinterpret_cast<float4*>(&sT[tab][rr][0])[j] =
                reinterpret_cast<const float4*>(src + row * 16)[j];
        }
    }
    __syncthreads();

    // ---- stage B: lanes (g,h), exactly 2 waves ----
    if (t < AGRP * 8) {
        int g = t >> 3, h = t & 7;
        int bn = bn0 + g;
        int b = bn / NN;
        int lb = (b - b0) * LL;
        float f[12];
        {
            const float4* fr = reinterpret_cast<const float4*>(flow + bn * LL);
            float4 f0 = fr[0], f1 = fr[1], f2 = fr[2];
            f[0] = f0.x; f[1] = f0.y; f[2] = f0.z; f[3] = f0.w;
            f[4] = f1.x; f[5] = f1.y; f[6] = f1.z; f[7] = f1.w;
            f[8] = f2.x; f[9] = f2.y; f[10] = f2.z; f[11] = f2.w;
        }
        float wqx = sWs[2 * h], wqy = sWs[2 * h + 1];
        float wkx = sWs[16 + 2 * h], wky = sWs[16 + 2 * h + 1];
        float wvx = sWs[32 + 2 * h], wvy = sWs[32 + 2 * h + 1];
        float kx[12], ky[12], vx[12], vy[12];
#pragma unroll
        for (int m = 0; m < LL; m++) {
            float2 tk = *reinterpret_cast<const float2*>(&sT[1][lb + m][2 * h]);
            float2 tv = *reinterpret_cast<const float2*>(&sT[2][lb + m][2 * h]);
            kx[m] = tk.x + f[m] * wkx; ky[m] = tk.y + f[m] * wky;
            vx[m] = tv.x + f[m] * wvx; vy[m] = tv.y + f[m] * wvy;
        }
#pragma unroll
        for (int l = 0; l < LL; l++) {
            float2 tq = *reinterpret_cast<const float2*>(&sT[0][lb + l][2 * h]);
            float qx = tq.x + f[l] * wqx, qy = tq.y + f[l] * wqy;
            float s[12];
            float sum = 0.f;
#pragma unroll
            for (int m = 0; m < LL; m++) {
                s[m] = __expf(qx * kx[m] + qy * ky[m]);  // 1/sqrt2 folded into q
                sum += s[m];
            }
            float a0 = 0.f, a1 = 0.f;
#pragma unroll
            for (int m = 0; m < LL; m++) { a0 += s[m] * vx[m]; a1 += s[m] * vy[m]; }
            float inv = 1.f / sum;
            float2 r; r.x = a0 * inv; r.y = a1 * inv;
            *reinterpret_cast<float2*>(&sA[g][l][2 * h]) = r;
        }
    }
    __syncthreads();

    // ---- stage C: lanes (g,l), all 192 ----
    {
        int g = t / LL, l = t - g * LL;
        int bn = bn0 + g;
        int b = bn / NN;
        int lb = (b - b0) * LL;
        float f = flow[bn * LL + l];
        float att[16];
        const float4* ar = reinterpret_cast<const float4*>(&sA[g][l][0]);
        float4 a0 = ar[0], a1 = ar[1], a2 = ar[2], a3 = ar[3];
        att[0] = a0.x; att[1] = a0.y; att[2] = a0.z; att[3] = a0.w;
        att[4] = a1.x; att[5] = a1.y; att[6] = a1.z; att[7] = a1.w;
        att[8] = a2.x; att[9] = a2.y; att[10] = a2.z; att[11] = a2.w;
        att[12] = a3.x; att[13] = a3.y; att[14] = a3.z; att[15] = a3.w;
        float o[16];
        const float4* to4 = reinterpret_cast<const float4*>(&sT[3][lb + l][0]);
#pragma unroll
        for (int j = 0; j < 4; j++) {
            float4 a = to4[j];
            o[4 * j] = a.x; o[4 * j + 1] = a.y; o[4 * j + 2] = a.z; o[4 * j + 3] = a.w;
        }
#pragma unroll
        for (int e = 0; e < 16; e++) {
            float ae = att[e];
            const float4* wo = reinterpret_cast<const float4*>(&sWo[e * 16]);
#pragma unroll
            for (int j = 0; j < 4; j++) {
                float4 w = wo[j];
                o[4 * j] += ae * w.x; o[4 * j + 1] += ae * w.y;
                o[4 * j + 2] += ae * w.z; o[4 * j + 3] += ae * w.w;
            }
        }
        unsigned pk[8];
#pragma unroll
        for (int j = 0; j < 8; j++) {
            unsigned u0 = __float_as_uint(o[2 * j] + f) + 0x8000u;
            unsigned u1 = __float_as_uint(o[2 * j + 1] + f) + 0x8000u;
            pk[j] = (u0 >> 16) | (u1 & 0xffff0000u);
        }
        uint4* dst = reinterpret_cast<uint4*>(xtcn + (size_t)bn * 192 + l * 16);
        uint4 d0; d0.x = pk[0]; d0.y = pk[1]; d0.z = pk[2]; d0.w = pk[3];
        uint4 d1; d1.x = pk[4]; d1.y = pk[5]; d1.z = pk[6]; d1.w = pk[7];
        dst[0] = d0; dst[1] = d1;
    }
}

// ---------------------------------------------------------------------------
// K4 v4: G1 = A_dyn @ flow[b], 2 batches per block; flow via scalar loads.
// ---------------------------------------------------------------------------
__global__ __launch_bounds__(256) void g1_kernel(const float* __restrict__ flow,
                                                 const float* __restrict__ AdT,
                                                 float* __restrict__ G1) {
    int bp = blockIdx.x, nt = blockIdx.y, t = threadIdx.x;
    int lane = t & 63;
    int l0 = (t >> 6) * 3;
    int l0u = __builtin_amdgcn_readfirstlane(l0);
    int n = nt * 128 + 2 * lane;
    int b0 = 2 * bp;
    const float* fb0 = flow + (size_t)b0 * (NN * LL);
    const float* fb1 = fb0 + NN * LL;

    float a000 = 0.f, a001 = 0.f, a002 = 0.f;
    float a010 = 0.f, a011 = 0.f, a012 = 0.f;
    float a100 = 0.f, a101 = 0.f, a102 = 0.f;
    float a110 = 0.f, a111 = 0.f, a112 = 0.f;
#pragma unroll 4
    for (int m = 0; m < NN; m++) {
        float2 w = reinterpret_cast<const float2*>(AdT + (size_t)m * ADTS + nt * 128)[lane];
        const float* r0 = fb0 + m * LL + l0u;
        const float* r1 = fb1 + m * LL + l0u;
        float p0 = r0[0], p1 = r0[1], p2 = r0[2];
        float q0 = r1[0], q1 = r1[1], q2 = r1[2];
        a000 += w.x * p0; a001 += w.x * p1; a002 += w.x * p2;
        a010 += w.y * p0; a011 += w.y * p1; a012 += w.y * p2;
        a100 += w.x * q0; a101 += w.x * q1; a102 += w.x * q2;
        a110 += w.y * q0; a111 += w.y * q1; a112 += w.y * q2;
    }
    if (n < NN) {
        float* d0 = G1 + ((size_t)b0 * NN + n) * LL + l0;
        d0[0] = a000; d0[1] = a001; d0[2] = a002;
        float* d1 = G1 + ((size_t)(b0 + 1) * NN + n) * LL + l0;
        d1[0] = a100; d1[1] = a101; d1[2] = a102;
    }
    if (n + 1 < NN) {
        float* d0 = G1 + ((size_t)b0 * NN + n + 1) * LL + l0;
        d0[0] = a010; d0[1] = a011; d0[2] = a012;
        float* d1 = G1 + ((size_t)(b0 + 1) * NN + n + 1) * LL + l0;
        d1[0] = a110; d1[1] = a111; d1[2] = a112;
    }
}

// ---------------------------------------------------------------------------
// K5 v7 (R9 exact — best measured final: 68.5us @ 74% occupancy):
// fused graph-mix + per-vertex MLP, XCD-locality grid (64, 307).
// No sW1T/sNid/sNw/sG1 extras (R11 showed they cost 4.5us via VGPR/occ).
// ---------------------------------------------------------------------------
__global__ __launch_bounds__(256) void final_kernel(
    const unsigned short* __restrict__ xtcn, const float* __restrict__ G1,
    const float* __restrict__ Wg, const float* __restrict__ Wt,
    const float* __restrict__ bg, const float* __restrict__ W1,
    const float* __restrict__ b1, const float* __restrict__ W2,
    const float* __restrict__ b2, const int* __restrict__ ncnt,
    const int* __restrict__ nidx, const float* __restrict__ nw,
    float* __restrict__ out) {
    __shared__ __align__(16) float sWt[512];
    __shared__ __align__(16) float sW1[256];
    __shared__ __align__(16) float sWg[32];
    __shared__ __align__(16) float sBg[32];
    __shared__ float sB1[8], sW2[8];
    __shared__ __align__(16) float sY[4][240];      // stride 20 per l
    __shared__ __align__(16) float4 sHID[4][120];   // stride 10 float4 per l
    __shared__ float sH1[4][96];

    int t = threadIdx.x;
    int by = blockIdx.x;          // batch group (XCD selector)
    int n  = blockIdx.y;          // vertex
    int w = t >> 6, t64 = t & 63;
    int b = by * 4 + w;

    // stage weights
    sW1[t] = W1[n * 256 + t];
    sWt[t] = Wt[t];
    sWt[t + 256] = Wt[t + 256];
    if (t < 32) sWg[t] = Wg[t];
    else if (t < 64) sBg[t - 32] = bg[t - 32];
    else if (t < 72) sB1[t - 64] = b1[n * 8 + (t - 64)];
    else if (t < 80) sW2[t - 72] = W2[n * 8 + (t - 72)];
    float vb2 = b2[n];
    int cnt = ncnt[n];
    __syncthreads();

    // sparse gather (bf16): lane t64<48 owns elements 4*t64 .. 4*t64+3
    if (t64 < 48) {
        float y0 = 0.f, y1 = 0.f, y2 = 0.f, y3 = 0.f;
        const unsigned short* base = xtcn + (size_t)b * NN * 192;
        int i = 0;
        for (; i + 3 < cnt; i += 4) {
            int m0 = nidx[n * NBRCAP + i],     m1 = nidx[n * NBRCAP + i + 1];
            int m2 = nidx[n * NBRCAP + i + 2], m3 = nidx[n * NBRCAP + i + 3];
            float w0 = nw[n * NBRCAP + i],     w1 = nw[n * NBRCAP + i + 1];
            float w2 = nw[n * NBRCAP + i + 2], w3 = nw[n * NBRCAP + i + 3];
            uint2 p0 = reinterpret_cast<const uint2*>(base + m0 * 192)[t64];
            uint2 p1 = reinterpret_cast<const uint2*>(base + m1 * 192)[t64];
            uint2 p2 = reinterpret_cast<const uint2*>(base + m2 * 192)[t64];
            uint2 p3 = reinterpret_cast<const uint2*>(base + m3 * 192)[t64];
            y0 += w0 * bf_lo(p0.x) + w1 * bf_lo(p1.x) + w2 * bf_lo(p2.x) + w3 * bf_lo(p3.x);
            y1 += w0 * bf_hi(p0.x) + w1 * bf_hi(p1.x) + w2 * bf_hi(p2.x) + w3 * bf_hi(p3.x);
            y2 += w0 * bf_lo(p0.y) + w1 * bf_lo(p1.y) + w2 * bf_lo(p2.y) + w3 * bf_lo(p3.y);
            y3 += w0 * bf_hi(p0.y) + w1 * bf_hi(p1.y) + w2 * bf_hi(p2.y) + w3 * bf_hi(p3.y);
        }
        for (; i < cnt; i++) {
            int ma = nidx[n * NBRCAP + i];
            float wa = nw[n * NBRCAP + i];
            uint2 pa = reinterpret_cast<const uint2*>(base + ma * 192)[t64];
            y0 += wa * bf_lo(pa.x); y1 += wa * bf_hi(pa.x);
            y2 += wa * bf_lo(pa.y); y3 += wa * bf_hi(pa.y);
        }
        int l = t64 >> 2, p = t64 & 3;
        reinterpret_cast<float4*>(&sY[w][l * 20])[p] = mkf4(y0, y1, y2, y3);
    }
    __syncthreads();

    // hid = relu(G1*Wg + y@Wt + bg): 384 jobs over 256 lanes
#pragma unroll
    for (int p = 0; p < 2; p++) {
        int jb = t + p * 256;
        if (jb < 384) {
            int w2 = jb / 96, c = jb - w2 * 96;
            int b2i = by * 4 + w2;
            int l = c >> 3, j = c & 7;
            float g = G1[((size_t)b2i * NN + n) * LL + l];
            float4 wg = reinterpret_cast<const float4*>(sWg)[j];
            float4 acc = reinterpret_cast<const float4*>(sBg)[j];
            acc.x += g * wg.x; acc.y += g * wg.y; acc.z += g * wg.z; acc.w += g * wg.w;
            const float4* yr = reinterpret_cast<const float4*>(&sY[w2][l * 20]);
            float4 v0 = yr[0], v1 = yr[1], v2 = yr[2], v3 = yr[3];
            float ye[16] = {v0.x, v0.y, v0.z, v0.w, v1.x, v1.y, v1.z, v1.w,
                            v2.x, v2.y, v2.z, v2.w, v3.x, v3.y, v3.z, v3.w};
#pragma unroll
            for (int d = 0; d < 16; d++) {
                float4 wt = reinterpret_cast<const float4*>(sWt)[d * 8 + j];
                acc.x += ye[d] * wt.x; acc.y += ye[d] * wt.y;
                acc.z += ye[d] * wt.z; acc.w += ye[d] * wt.w;
            }
            acc.x = fmaxf(acc.x, 0.f); acc.y = fmaxf(acc.y, 0.f);
            acc.z = fmaxf(acc.z, 0.f); acc.w = fmaxf(acc.w, 0.f);
            sHID[w2][l * 10 + j] = acc;
        }
    }
    __syncthreads();

    // h1 = relu(hid @ W1[n] + b1[n]): 384 jobs over 256 lanes
#pragma unroll
    for (int p = 0; p < 2; p++) {
        int jb = t + p * 256;
        if (jb < 384) {
            int w2 = jb / 96, o = jb - w2 * 96;
            int l = o >> 3, oo = o & 7;
            float acc = sB1[oo];
            float he[32];
#pragma unroll
            for (int k = 0; k < 8; k++) {
                float4 hv = sHID[w2][l * 10 + k];
                he[4 * k + 0] = hv.x; he[4 * k + 1] = hv.y;
                he[4 * k + 2] = hv.z; he[4 * k + 3] = hv.w;
            }
#pragma unroll
            for (int c = 0; c < 32; c++) acc += he[c] * sW1[c * 8 + oo];
            sH1[w2][o] = fmaxf(acc, 0.f);
        }
    }
    __syncthreads();

    // out = h1 @ W2[n] + b2[n]: 48 jobs
    if (t < 48) {
        int w2 = t / 12, l = t - w2 * 12;
        const float4* h4 = reinterpret_cast<const float4*>(&sH1[w2][l * 8]);
        float4 ha = h4[0], hb = h4[1];
        const float4* w4 = reinterpret_cast<const float4*>(sW2);
        float4 wa = w4[0], wb = w4[1];
        float acc = vb2 + ha.x * wa.x + ha.y * wa.y + ha.z * wa.z + ha.w * wa.w
                        + hb.x * wb.x + hb.y * wb.y + hb.z * wb.z + hb.w * wb.w;
        out[((size_t)(by * 4 + w2) * NN + n) * LL + l] = acc;
    }
}

// ---------------------------------------------------------------------------
extern "C" void kernel_launch(void* const* d_in, const int* in_sizes, int n_in,
                              void* d_out, int out_size, void* d_ws, size_t ws_size,
                              hipStream_t stream) {
    const float* flow = (const float*)d_in[0];
    const int* dayc   = (const int*)d_in[1];
    const int* weekc  = (const int*)d_in[2];
    const float* adj  = (const float*)d_in[3];
    const float* demb = (const float*)d_in[4];
    const float* wemb = (const float*)d_in[5];
    const float* Wq = (const float*)d_in[6];  const float* bq = (const float*)d_in[7];
    const float* Wk = (const float*)d_in[8];  const float* bk = (const float*)d_in[9];
    const float* Wv = (const float*)d_in[10]; const float* bv = (const float*)d_in[11];
    const float* Wo = (const float*)d_in[12]; const float* bo = (const float*)d_in[13];
    const float* Wg = (const float*)d_in[14]; const float* Wt = (const float*)d_in[15];
    const float* bg = (const float*)d_in[16];
    const float* W1 = (const float*)d_in[17]; const float* b1 = (const float*)d_in[18];
    const float* W2 = (const float*)d_in[19]; const float* b2 = (const float*)d_in[20];
    float* out = (float*)d_out;
    float* ws  = (float*)d_ws;

    unsigned short* xtcn = (unsigned short*)(ws + 0);   // bf16 region
    float* TEK  = ws + OFF_TEK;   // upper half of xtcn float region
    float* G1   = ws + OFF_G1;
    float* AdT  = ws + OFF_ADT;
    float* TEQ  = ws + OFF_TEQ;
    float* TEV  = ws + OFF_TEV;
    float* TEO  = ws + OFF_TEO;
    float* his  = ws + OFF_HIS;
    float* nw   = ws + OFF_NW;
    int*   nidx = (int*)(ws + OFF_NIDX);
    int*   ncnt = (int*)(ws + OFF_NCNT);

    prep_kernel<<<821, 256, 0, stream>>>(flow, dayc, weekc, demb, wemb,
                                         Wq, bq, Wk, bk, Wv, bv, bo, adj,
                                         his, TEQ, TEK, TEV, TEO, ncnt, nidx, nw);
    adyn_kernel<<<NN, 256, 0, stream>>>(his, AdT);
    attn_kernel<<<NBN / AGRP, 192, 0, stream>>>(flow, TEQ, TEK, TEV, TEO,
                                                Wq, Wk, Wv, Wo, xtcn);
    g1_kernel<<<dim3(NB / 2, 3), 256, 0, stream>>>(flow, AdT, G1);
    final_kernel<<<dim3(64, NN), 256, 0, stream>>>(xtcn, G1, Wg, Wt, bg, W1, b1, W2, b2,
                                                   ncnt, nidx, nw, out);
}